// Round 5
// baseline (579.545 us; speedup 1.0000x reference)
//
#include <hip/hip_runtime.h>
#include <hip/hip_bf16.h>
#include <stdint.h>

#define S_LEN   2048
#define DIN     2048
#define NHEADS  32
#define HDIM    64
#define NKV     8

typedef __bf16 bf16x8 __attribute__((ext_vector_type(8)));
typedef float  f32x4  __attribute__((ext_vector_type(4)));

#define AS1(p) ((__attribute__((address_space(1))) void*)(void*)(p))
#define AS3(p) ((__attribute__((address_space(3))) void*)(p))
#define MFMA_BF16 __builtin_amdgcn_mfma_f32_16x16x32_bf16

#if __has_builtin(__builtin_amdgcn_exp2f)
#define EXP2F(x) __builtin_amdgcn_exp2f(x)
#else
#define EXP2F(x) exp2f(x)
#endif

static __device__ __forceinline__ unsigned short f2bf(float f) {
  unsigned int x = __float_as_uint(f);
  return (unsigned short)((x + 0x7fffu + ((x >> 16) & 1u)) >> 16);
}

// ---------------- cast x (fp32 -> bf16), vectorized ----------------
__global__ __launch_bounds__(256) void cast_x_kernel(const float* __restrict__ x,
                                                     unsigned short* __restrict__ xb, int n4) {
  int i = blockIdx.x * 256 + threadIdx.x;
  if (i >= n4) return;
  float4 f = ((const float4*)x)[i];
  ushort4 o = make_ushort4(f2bf(f.x), f2bf(f.y), f2bf(f.z), f2bf(f.w));
  ((ushort4*)xb)[i] = o;
}

// ---------------- transpose + cast: src fp32 [K][N] -> dst bf16 [N][K] ----------------
__global__ __launch_bounds__(256) void transpose_cast(const float* __restrict__ src,
                                                      unsigned short* __restrict__ dst,
                                                      int K, int N) {
  __shared__ float t[32][33];
  int n0 = blockIdx.x * 32, k0 = blockIdx.y * 32;
  int x = threadIdx.x, y = threadIdx.y;
  #pragma unroll
  for (int j = 0; j < 32; j += 8)
    t[y + j][x] = src[(size_t)(k0 + y + j) * N + n0 + x];
  __syncthreads();
  #pragma unroll
  for (int j = 0; j < 32; j += 8)
    dst[(size_t)(n0 + y + j) * K + k0 + x] = f2bf(t[x][y + j]);
}

// ---------------- bf16 NT GEMM: C[M][N] fp32 = A[M][K] * Bt[N][K]^T ----------------
// m97 structure + XOR-swizzled LDS (swizzle realized via per-lane global address
// permutation in global_load_lds; consumer reads land 2-way/bank = free).
__global__ __launch_bounds__(256) void gemm_nt(const unsigned short* __restrict__ A,
                                               const unsigned short* __restrict__ Bt,
                                               float* __restrict__ C,
                                               int M, int N, int K) {
  __shared__ alignas(16) unsigned short As[128 * 32];
  __shared__ alignas(16) unsigned short Bs[128 * 32];
  const int tid = threadIdx.x;
  const int wave = tid >> 6, lane = tid & 63;
  const int g = lane >> 4, c = lane & 15;
  const int m0 = blockIdx.y * 128, n0 = blockIdx.x * 128;
  const int wm = (wave & 1) * 64, wn = (wave >> 1) * 64;

  f32x4 acc[4][4] = {};

  const int ch0 = wave * 2;
  const int p0 = ch0 * 64 + lane, p1 = p0 + 64;
  const int r0 = p0 >> 2, gc0 = ((p0 & 3) ^ ((r0 >> 1) & 3)) * 8;
  const int r1 = p1 >> 2, gc1 = ((p1 & 3) ^ ((r1 >> 1) & 3)) * 8;
  const unsigned short* a0 = A + (size_t)(m0 + r0) * K + gc0;
  const unsigned short* a1 = A + (size_t)(m0 + r1) * K + gc1;
  const unsigned short* b0 = Bt + (size_t)(n0 + r0) * K + gc0;
  const unsigned short* b1 = Bt + (size_t)(n0 + r1) * K + gc1;
  const int fswz = (c >> 1) & 3;   // f(row) for consumer rows (wm,i*16 are mult of 16)

  for (int k0 = 0; k0 < K; k0 += 32) {
    __syncthreads();
    __builtin_amdgcn_global_load_lds(AS1(a0 + k0), AS3(As + ch0 * 512), 16, 0, 0);
    __builtin_amdgcn_global_load_lds(AS1(a1 + k0), AS3(As + ch0 * 512 + 512), 16, 0, 0);
    __builtin_amdgcn_global_load_lds(AS1(b0 + k0), AS3(Bs + ch0 * 512), 16, 0, 0);
    __builtin_amdgcn_global_load_lds(AS1(b1 + k0), AS3(Bs + ch0 * 512 + 512), 16, 0, 0);
    __builtin_amdgcn_s_waitcnt(0);
    __syncthreads();

    bf16x8 af[4], bfr[4];
    #pragma unroll
    for (int i = 0; i < 4; i++)
      af[i] = *(const bf16x8*)(As + (wm + i * 16 + c) * 32 + (g ^ fswz) * 8);
    #pragma unroll
    for (int j = 0; j < 4; j++)
      bfr[j] = *(const bf16x8*)(Bs + (wn + j * 16 + c) * 32 + (g ^ fswz) * 8);
    #pragma unroll
    for (int i = 0; i < 4; i++)
      #pragma unroll
      for (int j = 0; j < 4; j++)
        acc[i][j] = MFMA_BF16(af[i], bfr[j], acc[i][j], 0, 0, 0);
  }

  #pragma unroll
  for (int i = 0; i < 4; i++)
    #pragma unroll
    for (int j = 0; j < 4; j++)
      #pragma unroll
      for (int r = 0; r < 4; r++)
        C[(size_t)(m0 + wm + i * 16 + g * 4 + r) * N + n0 + wn + j * 16 + c] = acc[i][j][r];
}

// ---------------- RMSNorm + RoPE for Q and K heads ----------------
// SC = log2(e)/sqrt(64) folded into Q here (attention uses exp2 with fixed max 0).
__global__ __launch_bounds__(256) void norm_rope(const float* __restrict__ QKV,
                                                 const float* __restrict__ cosb,
                                                 const float* __restrict__ sinb,
                                                 const float* __restrict__ q_scale,
                                                 const float* __restrict__ k_scale,
                                                 unsigned short* __restrict__ Qn,
                                                 unsigned short* __restrict__ Kn) {
  const int tid = threadIdx.x, w = tid >> 6, d = tid & 63;
  int task = blockIdx.x * 4 + w;
  const int hid = task % 40;
  const int row = task / 40;            // b*2048 + s
  const int b = row >> 11, s = row & 2047;
  float val, sc;
  if (hid < 32) {
    val = QKV[(size_t)row * 3072 + hid * 64 + d];
    sc = q_scale[d];
  } else {
    val = QKV[(size_t)row * 3072 + 2048 + (hid - 32) * 64 + d];
    sc = k_scale[d];
  }
  float v2 = val * val;
  #pragma unroll
  for (int off = 32; off; off >>= 1) v2 += __shfl_xor(v2, off);
  float t = val * (1.0f / sqrtf(v2 * (1.0f / 64.0f) + 1e-6f)) * sc;
  float partner = __shfl_xor(t, 32);
  float rot = (d < 32) ? -partner : partner;
  float o = t * cosb[s * 64 + d] + rot * sinb[s * 64 + d];
  if (hid < 32) o *= 0.18033688011112042f;   // fold softmax scale into Q
  unsigned short ob = f2bf(o);
  if (hid < 32) Qn[((size_t)(b * 32 + hid) * 2048 + s) * 64 + d] = ob;
  else          Kn[((size_t)(b * 8 + (hid - 32)) * 2048 + s) * 64 + d] = ob;
}

// ---------------- V transpose+cast: QKV fp32 V-cols -> Vt bf16 [b][kv][D][S] ----------------
__global__ __launch_bounds__(256) void v_transpose(const float* __restrict__ QKV,
                                                   unsigned short* __restrict__ Vt) {
  __shared__ float t[64][65];
  int bid = blockIdx.x;
  const int st = bid & 31, kv = (bid >> 5) & 7, b = bid >> 8;
  const int tid = threadIdx.x, lane = tid & 63, quad = tid >> 6;
  #pragma unroll
  for (int p = 0; p < 16; p++) {
    int sl = p * 4 + quad;
    t[sl][lane] = QKV[(size_t)(b * 2048 + st * 64 + sl) * 3072 + 2560 + kv * 64 + lane];
  }
  __syncthreads();
  size_t base = (size_t)(b * 8 + kv) * 64 * 2048;
  #pragma unroll
  for (int p = 0; p < 16; p++) {
    int dd = p * 4 + quad;
    Vt[base + (size_t)dd * 2048 + st * 64 + lane] = f2bf(t[lane][dd]);
  }
}

// ---------------- causal flash attention v4: one wave per block ----------------
// Each 64-thread block = one wave owning 32 q rows, walking its full causal kv
// range (avg 16.5 tiles). No cross-wave combine, no __syncthreads, LDS = 4.25 KB.
// Loop body as v3: K reg double-buffer, V early-issue, fixed-max softmax
// (p=exp2(s), SC folded into Q), wave-private swizzled P LDS round-trip with
// lgkmcnt-only wait. Only the final tile crosses the causal diagonal.
__global__ __launch_bounds__(64, 4) void attn_kernel(const unsigned short* __restrict__ Qn,
                                                     const unsigned short* __restrict__ Kn,
                                                     const unsigned short* __restrict__ Vt,
                                                     unsigned short* __restrict__ Outv) {
  __shared__ alignas(16) char PwB[4352];           // 32 rows x 128 B (swizzled) + pad

  const int lane = threadIdx.x & 63;
  const int g = lane >> 4, c = lane & 15;
  const int bid = blockIdx.x;
  const int qt = 63 - (bid >> 6);                  // longest blocks first
  const int h = (bid >> 1) & 31, b = bid & 1;
  const int kvh = h >> 2;
  const int Q0 = qt * 32;
  const unsigned short* Qp = Qn + ((size_t)(b * NHEADS + h) * S_LEN + Q0) * HDIM;
  const unsigned short* Kp = Kn + (size_t)(b * NKV + kvh) * S_LEN * HDIM;
  const unsigned short* Vp = Vt + (size_t)(b * NKV + kvh) * HDIM * S_LEN;  // [d][s]
  const int ntiles = (qt >> 1) + 1;

  // Q as B-operand: B[k=d][n=q], n = c, k = g*8+j (+t*32)
  bf16x8 bq[2][2];
  #pragma unroll
  for (int iq = 0; iq < 2; iq++)
    #pragma unroll
    for (int t = 0; t < 2; t++)
      bq[iq][t] = *(const bf16x8*)(Qp + (size_t)(iq * 16 + c) * HDIM + t * 32 + g * 8);

  f32x4 OT[4][2] = {};          // O^T tiles: [dt][iq], row=d, col=q
  f32x4 lv[2] = {};             // per-lane l partials

  bf16x8 ak[4][2];              // current K tile (A-operand: A[m=kv][k=d])
  #pragma unroll
  for (int jt = 0; jt < 4; jt++)
    #pragma unroll
    for (int t = 0; t < 2; t++)
      ak[jt][t] = *(const bf16x8*)(Kp + (size_t)(jt * 16 + c) * HDIM + t * 32 + g * 8);

  for (int ti = 0; ti < ntiles; ti++) {
    const int kv0 = ti * 64;

    // V tile (A-operand: A[m=d][k=kv]) — issued early, consumed after softmax
    bf16x8 av[4][2];
    #pragma unroll
    for (int dt = 0; dt < 4; dt++)
      #pragma unroll
      for (int t = 0; t < 2; t++)
        av[dt][t] = *(const bf16x8*)(Vp + (size_t)(dt * 16 + c) * S_LEN + kv0 + t * 32 + g * 8);

    // S^T = K · Q^T : rows kv, cols q
    f32x4 Sx[4][2] = {};
    #pragma unroll
    for (int t = 0; t < 2; t++)
      #pragma unroll
      for (int jt = 0; jt < 4; jt++)
        #pragma unroll
        for (int iq = 0; iq < 2; iq++)
          Sx[jt][iq] = MFMA_BF16(ak[jt][t], bq[iq][t], Sx[jt][iq], 0, 0, 0);

    // prefetch next K tile while softmax/PV runs
    bf16x8 akn[4][2];
    if (ti + 1 < ntiles) {
      const int kvn = kv0 + 64;
      #pragma unroll
      for (int jt = 0; jt < 4; jt++)
        #pragma unroll
        for (int t = 0; t < 2; t++)
          akn[jt][t] = *(const bf16x8*)(Kp + (size_t)(kvn + jt * 16 + c) * HDIM + t * 32 + g * 8);
    }

    if (ti == ntiles - 1) {     // only the final tile crosses the diagonal
      #pragma unroll
      for (int jt = 0; jt < 4; jt++)
        #pragma unroll
        for (int iq = 0; iq < 2; iq++)
          #pragma unroll
          for (int r = 0; r < 4; r++) {
            int kv = kv0 + jt * 16 + g * 4 + r;
            int q  = Q0 + iq * 16 + c;
            if (kv > q) Sx[jt][iq][r] = -1e30f;
          }
    }

    // fixed-max softmax: p = exp2(s); accumulate l per-lane; pack P -> LDS (swizzled)
    #pragma unroll
    for (int jt = 0; jt < 4; jt++)
      #pragma unroll
      for (int iq = 0; iq < 2; iq++) {
        f32x4 p;
        #pragma unroll
        for (int r = 0; r < 4; r++) p[r] = EXP2F(Sx[jt][iq][r]);
        lv[iq] += p;
        uint32_t u0 = __float_as_uint(p[0]) + 0x8000u;
        uint32_t u1 = __float_as_uint(p[1]) + 0x8000u;
        uint32_t u2 = __float_as_uint(p[2]) + 0x8000u;
        uint32_t u3 = __float_as_uint(p[3]) + 0x8000u;
        uint32_t lo = __builtin_amdgcn_perm(u1, u0, 0x07060302u);
        uint32_t hi = __builtin_amdgcn_perm(u3, u2, 0x07060302u);
        int row = iq * 16 + c;                 // local q
        int bytecol = jt * 32 + g * 8;         // kv-contiguous bytes
        uint32_t off = row * 128 + (((bytecol >> 4) ^ (row & 7)) << 4) + (bytecol & 15);
        *(uint2*)(PwB + off) = make_uint2(lo, hi);
      }
    __builtin_amdgcn_s_waitcnt(0xC07F);        // lgkmcnt(0) only — keep VMEM in flight

    // P as B-operand: B[k=kv][n=q]; read back swizzled b128 (wave-private)
    bf16x8 bp[2][2];
    #pragma unroll
    for (int iq = 0; iq < 2; iq++)
      #pragma unroll
      for (int t = 0; t < 2; t++) {
        int row = iq * 16 + c;
        int bytecol = t * 64 + g * 16;
        uint32_t off = row * 128 + (((bytecol >> 4) ^ (row & 7)) << 4);
        bp[iq][t] = *(const bf16x8*)(PwB + off);
      }
    #pragma unroll
    for (int t = 0; t < 2; t++)
      #pragma unroll
      for (int dt = 0; dt < 4; dt++)
        #pragma unroll
        for (int iq = 0; iq < 2; iq++)
          OT[dt][iq] = MFMA_BF16(av[dt][t], bp[iq][t], OT[dt][iq], 0, 0, 0);

    #pragma unroll
    for (int jt = 0; jt < 4; jt++)
      #pragma unroll
      for (int t = 0; t < 2; t++)
        ak[jt][t] = akn[jt][t];
  }

  // l: sum lane partials (kv mod 16 split across g) -> butterfly over g
  float inv[2];
  #pragma unroll
  for (int iq = 0; iq < 2; iq++) {
    float s = lv[iq][0] + lv[iq][1] + lv[iq][2] + lv[iq][3];
    s += __shfl_xor(s, 16);
    s += __shfl_xor(s, 32);
    inv[iq] = 1.0f / s;
  }

  // write O: lane holds d = dt*16+g*4+{0..3}, q = Q0+iq*16+c -> 8B stores
  #pragma unroll
  for (int iq = 0; iq < 2; iq++) {
    const int q = Q0 + iq * 16 + c;
    unsigned short* orow = Outv + (size_t)(b * S_LEN + q) * (NHEADS * HDIM) + h * HDIM;
    #pragma unroll
    for (int dt = 0; dt < 4; dt++) {
      uint32_t u0 = __float_as_uint(OT[dt][iq][0] * inv[iq]) + 0x8000u;
      uint32_t u1 = __float_as_uint(OT[dt][iq][1] * inv[iq]) + 0x8000u;
      uint32_t u2 = __float_as_uint(OT[dt][iq][2] * inv[iq]) + 0x8000u;
      uint32_t u3 = __float_as_uint(OT[dt][iq][3] * inv[iq]) + 0x8000u;
      uint32_t lo = __builtin_amdgcn_perm(u1, u0, 0x07060302u);
      uint32_t hi = __builtin_amdgcn_perm(u3, u2, 0x07060302u);
      *(uint2*)(orow + dt * 16 + g * 4) = make_uint2(lo, hi);
    }
  }
}

extern "C" void kernel_launch(void* const* d_in, const int* in_sizes, int n_in,
                              void* d_out, int out_size, void* d_ws, size_t ws_size,
                              hipStream_t stream) {
  const float* x       = (const float*)d_in[0];
  // d_in[1] = mask (causal, implemented analytically)
  const float* cosb    = (const float*)d_in[2];
  const float* sinb    = (const float*)d_in[3];
  const float* Wq      = (const float*)d_in[4];
  const float* Wk      = (const float*)d_in[5];
  const float* Wv      = (const float*)d_in[6];
  const float* Wo      = (const float*)d_in[7];
  const float* q_scale = (const float*)d_in[8];
  const float* k_scale = (const float*)d_in[9];

  char* ws = (char*)d_ws;
  unsigned short* xb   = (unsigned short*)(ws);                       // 16 MiB: x bf16 [4096][2048]
  unsigned short* wcat = (unsigned short*)(ws + (16ull << 20));       // 12 MiB: Wt [3072][2048]
  unsigned short* wo_t = (unsigned short*)(ws + (28ull << 20));       //  8 MiB: Wo_t [2048][2048]
  float*          qkv  = (float*)        (ws + (36ull << 20));        // 48 MiB: QKV fp32 [4096][3072]
  unsigned short* qn   = (unsigned short*)(ws + (84ull << 20));       // 16 MiB: Q bf16 [b][h][s][d]
  unsigned short* kn   = (unsigned short*)(ws + (100ull << 20));      //  4 MiB: K bf16 [b][kv][s][d]
  unsigned short* vt   = (unsigned short*)(ws + (104ull << 20));      //  4 MiB: V^T bf16 [b][kv][d][s]
  unsigned short* vec  = (unsigned short*)(ws + (36ull << 20));       // alias qkv (dead after v_transpose)

  cast_x_kernel<<<8192, 256, 0, stream>>>(x, xb, 2097152);
  dim3 tb(32, 8);
  transpose_cast<<<dim3(64, 64), tb, 0, stream>>>(Wq, wcat,               2048, 2048);
  transpose_cast<<<dim3(16, 64), tb, 0, stream>>>(Wk, wcat + 2048 * 2048, 2048, 512);
  transpose_cast<<<dim3(16, 64), tb, 0, stream>>>(Wv, wcat + 2560 * 2048, 2048, 512);
  transpose_cast<<<dim3(64, 64), tb, 0, stream>>>(Wo, wo_t,               2048, 2048);

  gemm_nt<<<dim3(24, 32), 256, 0, stream>>>(xb, wcat, qkv, 4096, 3072, 2048);
  norm_rope<<<40960, 256, 0, stream>>>(qkv, cosb, sinb, q_scale, k_scale, qn, kn);
  v_transpose<<<512, 256, 0, stream>>>(qkv, vt);
  attn_kernel<<<4096, 64, 0, stream>>>(qn, kn, vt, vec);
  gemm_nt<<<dim3(16, 32), 256, 0, stream>>>(vec, wo_t, (float*)d_out, 4096, 2048, 2048);
}

// Round 6
// 423.213 us; speedup vs baseline: 1.3694x; 1.3694x over previous
//
#include <hip/hip_runtime.h>
#include <hip/hip_bf16.h>
#include <stdint.h>

#define S_LEN   2048
#define DIN     2048
#define NHEADS  32
#define HDIM    64
#define NKV     8

typedef __bf16 bf16x8 __attribute__((ext_vector_type(8)));
typedef float  f32x4  __attribute__((ext_vector_type(4)));

#define AS1(p) ((__attribute__((address_space(1))) void*)(void*)(p))
#define AS3(p) ((__attribute__((address_space(3))) void*)(p))
#define MFMA_BF16 __builtin_amdgcn_mfma_f32_16x16x32_bf16

#if __has_builtin(__builtin_amdgcn_exp2f)
#define EXP2F(x) __builtin_amdgcn_exp2f(x)
#else
#define EXP2F(x) exp2f(x)
#endif

static __device__ __forceinline__ unsigned short f2bf(float f) {
  unsigned int x = __float_as_uint(f);
  return (unsigned short)((x + 0x7fffu + ((x >> 16) & 1u)) >> 16);
}

// ---------------- cast x (fp32 -> bf16), vectorized ----------------
__global__ __launch_bounds__(256) void cast_x_kernel(const float* __restrict__ x,
                                                     unsigned short* __restrict__ xb, int n4) {
  int i = blockIdx.x * 256 + threadIdx.x;
  if (i >= n4) return;
  float4 f = ((const float4*)x)[i];
  ushort4 o = make_ushort4(f2bf(f.x), f2bf(f.y), f2bf(f.z), f2bf(f.w));
  ((ushort4*)xb)[i] = o;
}

// ---------------- transpose + cast: src fp32 [K][N] -> dst bf16 [N][K] ----------------
__global__ __launch_bounds__(256) void transpose_cast(const float* __restrict__ src,
                                                      unsigned short* __restrict__ dst,
                                                      int K, int N) {
  __shared__ float t[32][33];
  int n0 = blockIdx.x * 32, k0 = blockIdx.y * 32;
  int x = threadIdx.x, y = threadIdx.y;
  #pragma unroll
  for (int j = 0; j < 32; j += 8)
    t[y + j][x] = src[(size_t)(k0 + y + j) * N + n0 + x];
  __syncthreads();
  #pragma unroll
  for (int j = 0; j < 32; j += 8)
    dst[(size_t)(n0 + y + j) * K + k0 + x] = f2bf(t[x][y + j]);
}

// ---------------- bf16 NT GEMM: C[M][N] fp32 = A[M][K] * Bt[N][K]^T ----------------
// m97 structure + XOR-swizzled LDS (swizzle realized via per-lane global address
// permutation in global_load_lds; consumer reads land 2-way/bank = free).
__global__ __launch_bounds__(256) void gemm_nt(const unsigned short* __restrict__ A,
                                               const unsigned short* __restrict__ Bt,
                                               float* __restrict__ C,
                                               int M, int N, int K) {
  __shared__ alignas(16) unsigned short As[128 * 32];
  __shared__ alignas(16) unsigned short Bs[128 * 32];
  const int tid = threadIdx.x;
  const int wave = tid >> 6, lane = tid & 63;
  const int g = lane >> 4, c = lane & 15;
  const int m0 = blockIdx.y * 128, n0 = blockIdx.x * 128;
  const int wm = (wave & 1) * 64, wn = (wave >> 1) * 64;

  f32x4 acc[4][4] = {};

  const int ch0 = wave * 2;
  const int p0 = ch0 * 64 + lane, p1 = p0 + 64;
  const int r0 = p0 >> 2, gc0 = ((p0 & 3) ^ ((r0 >> 1) & 3)) * 8;
  const int r1 = p1 >> 2, gc1 = ((p1 & 3) ^ ((r1 >> 1) & 3)) * 8;
  const unsigned short* a0 = A + (size_t)(m0 + r0) * K + gc0;
  const unsigned short* a1 = A + (size_t)(m0 + r1) * K + gc1;
  const unsigned short* b0 = Bt + (size_t)(n0 + r0) * K + gc0;
  const unsigned short* b1 = Bt + (size_t)(n0 + r1) * K + gc1;
  const int fswz = (c >> 1) & 3;   // f(row) for consumer rows (wm,i*16 are mult of 16)

  for (int k0 = 0; k0 < K; k0 += 32) {
    __syncthreads();
    __builtin_amdgcn_global_load_lds(AS1(a0 + k0), AS3(As + ch0 * 512), 16, 0, 0);
    __builtin_amdgcn_global_load_lds(AS1(a1 + k0), AS3(As + ch0 * 512 + 512), 16, 0, 0);
    __builtin_amdgcn_global_load_lds(AS1(b0 + k0), AS3(Bs + ch0 * 512), 16, 0, 0);
    __builtin_amdgcn_global_load_lds(AS1(b1 + k0), AS3(Bs + ch0 * 512 + 512), 16, 0, 0);
    __builtin_amdgcn_s_waitcnt(0);
    __syncthreads();

    bf16x8 af[4], bfr[4];
    #pragma unroll
    for (int i = 0; i < 4; i++)
      af[i] = *(const bf16x8*)(As + (wm + i * 16 + c) * 32 + (g ^ fswz) * 8);
    #pragma unroll
    for (int j = 0; j < 4; j++)
      bfr[j] = *(const bf16x8*)(Bs + (wn + j * 16 + c) * 32 + (g ^ fswz) * 8);
    #pragma unroll
    for (int i = 0; i < 4; i++)
      #pragma unroll
      for (int j = 0; j < 4; j++)
        acc[i][j] = MFMA_BF16(af[i], bfr[j], acc[i][j], 0, 0, 0);
  }

  #pragma unroll
  for (int i = 0; i < 4; i++)
    #pragma unroll
    for (int j = 0; j < 4; j++)
      #pragma unroll
      for (int r = 0; r < 4; r++)
        C[(size_t)(m0 + wm + i * 16 + g * 4 + r) * N + n0 + wn + j * 16 + c] = acc[i][j][r];
}

// ---------------- RMSNorm + RoPE for Q and K heads ----------------
// SC = log2(e)/sqrt(64) folded into Q here (attention uses exp2 with fixed max 0).
__global__ __launch_bounds__(256) void norm_rope(const float* __restrict__ QKV,
                                                 const float* __restrict__ cosb,
                                                 const float* __restrict__ sinb,
                                                 const float* __restrict__ q_scale,
                                                 const float* __restrict__ k_scale,
                                                 unsigned short* __restrict__ Qn,
                                                 unsigned short* __restrict__ Kn) {
  const int tid = threadIdx.x, w = tid >> 6, d = tid & 63;
  int task = blockIdx.x * 4 + w;
  const int hid = task % 40;
  const int row = task / 40;            // b*2048 + s
  const int b = row >> 11, s = row & 2047;
  float val, sc;
  if (hid < 32) {
    val = QKV[(size_t)row * 3072 + hid * 64 + d];
    sc = q_scale[d];
  } else {
    val = QKV[(size_t)row * 3072 + 2048 + (hid - 32) * 64 + d];
    sc = k_scale[d];
  }
  float v2 = val * val;
  #pragma unroll
  for (int off = 32; off; off >>= 1) v2 += __shfl_xor(v2, off);
  float t = val * (1.0f / sqrtf(v2 * (1.0f / 64.0f) + 1e-6f)) * sc;
  float partner = __shfl_xor(t, 32);
  float rot = (d < 32) ? -partner : partner;
  float o = t * cosb[s * 64 + d] + rot * sinb[s * 64 + d];
  if (hid < 32) o *= 0.18033688011112042f;   // fold softmax scale into Q
  unsigned short ob = f2bf(o);
  if (hid < 32) Qn[((size_t)(b * 32 + hid) * 2048 + s) * 64 + d] = ob;
  else          Kn[((size_t)(b * 8 + (hid - 32)) * 2048 + s) * 64 + d] = ob;
}

// ---------------- V transpose+cast: QKV fp32 V-cols -> Vt bf16 [b][kv][D][S] ----------------
__global__ __launch_bounds__(256) void v_transpose(const float* __restrict__ QKV,
                                                   unsigned short* __restrict__ Vt) {
  __shared__ float t[64][65];
  int bid = blockIdx.x;
  const int st = bid & 31, kv = (bid >> 5) & 7, b = bid >> 8;
  const int tid = threadIdx.x, lane = tid & 63, quad = tid >> 6;
  #pragma unroll
  for (int p = 0; p < 16; p++) {
    int sl = p * 4 + quad;
    t[sl][lane] = QKV[(size_t)(b * 2048 + st * 64 + sl) * 3072 + 2560 + kv * 64 + lane];
  }
  __syncthreads();
  size_t base = (size_t)(b * 8 + kv) * 64 * 2048;
  #pragma unroll
  for (int p = 0; p < 16; p++) {
    int dd = p * 4 + quad;
    Vt[base + (size_t)dd * 2048 + st * 64 + lane] = f2bf(t[lane][dd]);
  }
}

// ---------------- causal flash attention v5: 4 independent waves / block ----------------
// Block = 256 threads = 4 waves; wave w owns head hg*4+w for the block's (b, qt)
// and walks its FULL causal kv range (no cross-wave combine, no __syncthreads).
// All 4 waves: identical tile count (same qt) and same KV head (kvh = hg) -> zero
// intra-block imbalance + K/V L1 reuse. 256-thr block restores R4's proven
// VGPR=128 no-spill allocation (R5's 64-thr + bounds cap caused 567 MB of spills).
__global__ __launch_bounds__(256) void attn_kernel(const unsigned short* __restrict__ Qn,
                                                   const unsigned short* __restrict__ Kn,
                                                   const unsigned short* __restrict__ Vt,
                                                   unsigned short* __restrict__ Outv) {
  __shared__ alignas(16) char smem[4 * 4352];

  const int tid = threadIdx.x, w = tid >> 6, lane = tid & 63;
  const int g = lane >> 4, c = lane & 15;
  const int bid = blockIdx.x;                      // [0, 1024)
  const int qt = 63 - (bid >> 4);                  // longest blocks first
  const int rem = bid & 15;
  const int hg = rem & 7, b = rem >> 3;
  const int h = hg * 4 + w;
  const int kvh = hg;
  const int Q0 = qt * 32;
  const unsigned short* Qp = Qn + ((size_t)(b * NHEADS + h) * S_LEN + Q0) * HDIM;
  const unsigned short* Kp = Kn + (size_t)(b * NKV + kvh) * S_LEN * HDIM;
  const unsigned short* Vp = Vt + (size_t)(b * NKV + kvh) * HDIM * S_LEN;  // [d][s]
  const int ntiles = (qt >> 1) + 1;
  char* PwB = smem + w * 4352;   // this wave's P buffer (32 rows x 128 B, swizzled)

  // Q as B-operand: B[k=d][n=q], n = c, k = g*8+j (+t*32)
  bf16x8 bq[2][2];
  #pragma unroll
  for (int iq = 0; iq < 2; iq++)
    #pragma unroll
    for (int t = 0; t < 2; t++)
      bq[iq][t] = *(const bf16x8*)(Qp + (size_t)(iq * 16 + c) * HDIM + t * 32 + g * 8);

  f32x4 OT[4][2] = {};          // O^T tiles: [dt][iq], row=d, col=q
  f32x4 lv[2] = {};             // per-lane l partials

  bf16x8 ak[4][2];              // current K tile (A-operand: A[m=kv][k=d])
  #pragma unroll
  for (int jt = 0; jt < 4; jt++)
    #pragma unroll
    for (int t = 0; t < 2; t++)
      ak[jt][t] = *(const bf16x8*)(Kp + (size_t)(jt * 16 + c) * HDIM + t * 32 + g * 8);

  for (int ti = 0; ti < ntiles; ti++) {
    const int kv0 = ti * 64;

    // V tile (A-operand: A[m=d][k=kv]) — issued early, consumed after softmax
    bf16x8 av[4][2];
    #pragma unroll
    for (int dt = 0; dt < 4; dt++)
      #pragma unroll
      for (int t = 0; t < 2; t++)
        av[dt][t] = *(const bf16x8*)(Vp + (size_t)(dt * 16 + c) * S_LEN + kv0 + t * 32 + g * 8);

    // S^T = K · Q^T : rows kv, cols q
    f32x4 Sx[4][2] = {};
    #pragma unroll
    for (int t = 0; t < 2; t++)
      #pragma unroll
      for (int jt = 0; jt < 4; jt++)
        #pragma unroll
        for (int iq = 0; iq < 2; iq++)
          Sx[jt][iq] = MFMA_BF16(ak[jt][t], bq[iq][t], Sx[jt][iq], 0, 0, 0);

    // prefetch next K tile while softmax/PV runs
    bf16x8 akn[4][2];
    if (ti + 1 < ntiles) {
      const int kvn = kv0 + 64;
      #pragma unroll
      for (int jt = 0; jt < 4; jt++)
        #pragma unroll
        for (int t = 0; t < 2; t++)
          akn[jt][t] = *(const bf16x8*)(Kp + (size_t)(kvn + jt * 16 + c) * HDIM + t * 32 + g * 8);
    }

    if (ti == ntiles - 1) {     // only the final tile crosses the diagonal
      #pragma unroll
      for (int jt = 0; jt < 4; jt++)
        #pragma unroll
        for (int iq = 0; iq < 2; iq++)
          #pragma unroll
          for (int r = 0; r < 4; r++) {
            int kv = kv0 + jt * 16 + g * 4 + r;
            int q  = Q0 + iq * 16 + c;
            if (kv > q) Sx[jt][iq][r] = -1e30f;
          }
    }

    // fixed-max softmax: p = exp2(s); accumulate l per-lane; pack P -> LDS (swizzled)
    #pragma unroll
    for (int jt = 0; jt < 4; jt++)
      #pragma unroll
      for (int iq = 0; iq < 2; iq++) {
        f32x4 p;
        #pragma unroll
        for (int r = 0; r < 4; r++) p[r] = EXP2F(Sx[jt][iq][r]);
        lv[iq] += p;
        uint32_t u0 = __float_as_uint(p[0]) + 0x8000u;
        uint32_t u1 = __float_as_uint(p[1]) + 0x8000u;
        uint32_t u2 = __float_as_uint(p[2]) + 0x8000u;
        uint32_t u3 = __float_as_uint(p[3]) + 0x8000u;
        uint32_t lo = __builtin_amdgcn_perm(u1, u0, 0x07060302u);
        uint32_t hi = __builtin_amdgcn_perm(u3, u2, 0x07060302u);
        int row = iq * 16 + c;                 // local q
        int bytecol = jt * 32 + g * 8;         // kv-contiguous bytes
        uint32_t off = row * 128 + (((bytecol >> 4) ^ (row & 7)) << 4) + (bytecol & 15);
        *(uint2*)(PwB + off) = make_uint2(lo, hi);
      }
    __builtin_amdgcn_s_waitcnt(0xC07F);        // lgkmcnt(0) only — keep VMEM in flight

    // P as B-operand: B[k=kv][n=q]; read back swizzled b128 (wave-private)
    bf16x8 bp[2][2];
    #pragma unroll
    for (int iq = 0; iq < 2; iq++)
      #pragma unroll
      for (int t = 0; t < 2; t++) {
        int row = iq * 16 + c;
        int bytecol = t * 64 + g * 16;
        uint32_t off = row * 128 + (((bytecol >> 4) ^ (row & 7)) << 4);
        bp[iq][t] = *(const bf16x8*)(PwB + off);
      }
    #pragma unroll
    for (int t = 0; t < 2; t++)
      #pragma unroll
      for (int dt = 0; dt < 4; dt++)
        #pragma unroll
        for (int iq = 0; iq < 2; iq++)
          OT[dt][iq] = MFMA_BF16(av[dt][t], bp[iq][t], OT[dt][iq], 0, 0, 0);

    #pragma unroll
    for (int jt = 0; jt < 4; jt++)
      #pragma unroll
      for (int t = 0; t < 2; t++)
        ak[jt][t] = akn[jt][t];
  }

  // l: sum lane partials (kv mod 16 split across g) -> butterfly over g
  float inv[2];
  #pragma unroll
  for (int iq = 0; iq < 2; iq++) {
    float s = lv[iq][0] + lv[iq][1] + lv[iq][2] + lv[iq][3];
    s += __shfl_xor(s, 16);
    s += __shfl_xor(s, 32);
    inv[iq] = 1.0f / s;
  }

  // write O: lane holds d = dt*16+g*4+{0..3}, q = Q0+iq*16+c -> 8B stores
  #pragma unroll
  for (int iq = 0; iq < 2; iq++) {
    const int q = Q0 + iq * 16 + c;
    unsigned short* orow = Outv + (size_t)(b * S_LEN + q) * (NHEADS * HDIM) + h * HDIM;
    #pragma unroll
    for (int dt = 0; dt < 4; dt++) {
      uint32_t u0 = __float_as_uint(OT[dt][iq][0] * inv[iq]) + 0x8000u;
      uint32_t u1 = __float_as_uint(OT[dt][iq][1] * inv[iq]) + 0x8000u;
      uint32_t u2 = __float_as_uint(OT[dt][iq][2] * inv[iq]) + 0x8000u;
      uint32_t u3 = __float_as_uint(OT[dt][iq][3] * inv[iq]) + 0x8000u;
      uint32_t lo = __builtin_amdgcn_perm(u1, u0, 0x07060302u);
      uint32_t hi = __builtin_amdgcn_perm(u3, u2, 0x07060302u);
      *(uint2*)(orow + dt * 16 + g * 4) = make_uint2(lo, hi);
    }
  }
}

extern "C" void kernel_launch(void* const* d_in, const int* in_sizes, int n_in,
                              void* d_out, int out_size, void* d_ws, size_t ws_size,
                              hipStream_t stream) {
  const float* x       = (const float*)d_in[0];
  // d_in[1] = mask (causal, implemented analytically)
  const float* cosb    = (const float*)d_in[2];
  const float* sinb    = (const float*)d_in[3];
  const float* Wq      = (const float*)d_in[4];
  const float* Wk      = (const float*)d_in[5];
  const float* Wv      = (const float*)d_in[6];
  const float* Wo      = (const float*)d_in[7];
  const float* q_scale = (const float*)d_in[8];
  const float* k_scale = (const float*)d_in[9];

  char* ws = (char*)d_ws;
  unsigned short* xb   = (unsigned short*)(ws);                       // 16 MiB: x bf16 [4096][2048]
  unsigned short* wcat = (unsigned short*)(ws + (16ull << 20));       // 12 MiB: Wt [3072][2048]
  unsigned short* wo_t = (unsigned short*)(ws + (28ull << 20));       //  8 MiB: Wo_t [2048][2048]
  float*          qkv  = (float*)        (ws + (36ull << 20));        // 48 MiB: QKV fp32 [4096][3072]
  unsigned short* qn   = (unsigned short*)(ws + (84ull << 20));       // 16 MiB: Q bf16 [b][h][s][d]
  unsigned short* kn   = (unsigned short*)(ws + (100ull << 20));      //  4 MiB: K bf16 [b][kv][s][d]
  unsigned short* vt   = (unsigned short*)(ws + (104ull << 20));      //  4 MiB: V^T bf16 [b][kv][d][s]
  unsigned short* vec  = (unsigned short*)(ws + (36ull << 20));       // alias qkv (dead after v_transpose)

  cast_x_kernel<<<8192, 256, 0, stream>>>(x, xb, 2097152);
  dim3 tb(32, 8);
  transpose_cast<<<dim3(64, 64), tb, 0, stream>>>(Wq, wcat,               2048, 2048);
  transpose_cast<<<dim3(16, 64), tb, 0, stream>>>(Wk, wcat + 2048 * 2048, 2048, 512);
  transpose_cast<<<dim3(16, 64), tb, 0, stream>>>(Wv, wcat + 2560 * 2048, 2048, 512);
  transpose_cast<<<dim3(64, 64), tb, 0, stream>>>(Wo, wo_t,               2048, 2048);

  gemm_nt<<<dim3(24, 32), 256, 0, stream>>>(xb, wcat, qkv, 4096, 3072, 2048);
  norm_rope<<<40960, 256, 0, stream>>>(qkv, cosb, sinb, q_scale, k_scale, qn, kn);
  v_transpose<<<512, 256, 0, stream>>>(qkv, vt);
  attn_kernel<<<1024, 256, 0, stream>>>(qn, kn, vt, vec);
  gemm_nt<<<dim3(16, 32), 256, 0, stream>>>(vec, wo_t, (float*)d_out, 4096, 2048, 2048);
}

// Round 7
// 410.553 us; speedup vs baseline: 1.4116x; 1.0308x over previous
//
#include <hip/hip_runtime.h>
#include <hip/hip_bf16.h>
#include <stdint.h>

#define S_LEN   2048
#define DIN     2048
#define NHEADS  32
#define HDIM    64
#define NKV     8

typedef __bf16 bf16x8 __attribute__((ext_vector_type(8)));
typedef float  f32x4  __attribute__((ext_vector_type(4)));

#define AS1(p) ((__attribute__((address_space(1))) void*)(void*)(p))
#define AS3(p) ((__attribute__((address_space(3))) void*)(p))
#define MFMA_BF16 __builtin_amdgcn_mfma_f32_16x16x32_bf16

#if __has_builtin(__builtin_amdgcn_exp2f)
#define EXP2F(x) __builtin_amdgcn_exp2f(x)
#else
#define EXP2F(x) exp2f(x)
#endif

static __device__ __forceinline__ unsigned short f2bf(float f) {
  unsigned int x = __float_as_uint(f);
  return (unsigned short)((x + 0x7fffu + ((x >> 16) & 1u)) >> 16);
}
static __device__ __forceinline__ float bf2f(unsigned short u) {
  return __uint_as_float((unsigned int)u << 16);
}

// ---------------- cast x (fp32 -> bf16), vectorized ----------------
__global__ __launch_bounds__(256) void cast_x_kernel(const float* __restrict__ x,
                                                     unsigned short* __restrict__ xb, int n4) {
  int i = blockIdx.x * 256 + threadIdx.x;
  if (i >= n4) return;
  float4 f = ((const float4*)x)[i];
  ushort4 o = make_ushort4(f2bf(f.x), f2bf(f.y), f2bf(f.z), f2bf(f.w));
  ((ushort4*)xb)[i] = o;
}

// ---------------- transpose + cast: src fp32 [K][N] -> dst bf16 [N][K] ----------------
__global__ __launch_bounds__(256) void transpose_cast(const float* __restrict__ src,
                                                      unsigned short* __restrict__ dst,
                                                      int K, int N) {
  __shared__ float t[32][33];
  int n0 = blockIdx.x * 32, k0 = blockIdx.y * 32;
  int x = threadIdx.x, y = threadIdx.y;
  #pragma unroll
  for (int j = 0; j < 32; j += 8)
    t[y + j][x] = src[(size_t)(k0 + y + j) * N + n0 + x];
  __syncthreads();
  #pragma unroll
  for (int j = 0; j < 32; j += 8)
    dst[(size_t)(n0 + y + j) * K + k0 + x] = f2bf(t[x][y + j]);
}

// ---------------- fused W transpose: [Wq|Wk|Wv] -> wcat bf16 [3072][2048] ----------------
__global__ __launch_bounds__(256) void transpose_cast_wqkv(const float* __restrict__ Wq,
                                                           const float* __restrict__ Wk,
                                                           const float* __restrict__ Wv,
                                                           unsigned short* __restrict__ dst) {
  __shared__ float t[32][33];
  int n0 = blockIdx.x * 32, k0 = blockIdx.y * 32;   // n0 in [0,3072)
  const float* src; int col0, srcN;
  if (n0 < 2048)      { src = Wq; col0 = n0;        srcN = 2048; }
  else if (n0 < 2560) { src = Wk; col0 = n0 - 2048; srcN = 512; }
  else                { src = Wv; col0 = n0 - 2560; srcN = 512; }
  int x = threadIdx.x, y = threadIdx.y;
  #pragma unroll
  for (int j = 0; j < 32; j += 8)
    t[y + j][x] = src[(size_t)(k0 + y + j) * srcN + col0 + x];
  __syncthreads();
  #pragma unroll
  for (int j = 0; j < 32; j += 8)
    dst[(size_t)(n0 + y + j) * 2048 + k0 + x] = f2bf(t[x][y + j]);
}

// ---------------- bf16 NT GEMM: C[M][N] = A[M][K] * Bt[N][K]^T (fp32 or bf16 out) ----
// m97 structure + XOR-swizzled LDS (swizzle realized via per-lane global address
// permutation in global_load_lds; consumer reads land 2-way/bank = free).
template <typename OutT>
__global__ __launch_bounds__(256) void gemm_nt(const unsigned short* __restrict__ A,
                                               const unsigned short* __restrict__ Bt,
                                               OutT* __restrict__ C,
                                               int M, int N, int K) {
  __shared__ alignas(16) unsigned short As[128 * 32];
  __shared__ alignas(16) unsigned short Bs[128 * 32];
  const int tid = threadIdx.x;
  const int wave = tid >> 6, lane = tid & 63;
  const int g = lane >> 4, c = lane & 15;
  const int m0 = blockIdx.y * 128, n0 = blockIdx.x * 128;
  const int wm = (wave & 1) * 64, wn = (wave >> 1) * 64;

  f32x4 acc[4][4] = {};

  const int ch0 = wave * 2;
  const int p0 = ch0 * 64 + lane, p1 = p0 + 64;
  const int r0 = p0 >> 2, gc0 = ((p0 & 3) ^ ((r0 >> 1) & 3)) * 8;
  const int r1 = p1 >> 2, gc1 = ((p1 & 3) ^ ((r1 >> 1) & 3)) * 8;
  const unsigned short* a0 = A + (size_t)(m0 + r0) * K + gc0;
  const unsigned short* a1 = A + (size_t)(m0 + r1) * K + gc1;
  const unsigned short* b0 = Bt + (size_t)(n0 + r0) * K + gc0;
  const unsigned short* b1 = Bt + (size_t)(n0 + r1) * K + gc1;
  const int fswz = (c >> 1) & 3;   // f(row) for consumer rows (wm,i*16 are mult of 16)

  for (int k0 = 0; k0 < K; k0 += 32) {
    __syncthreads();
    __builtin_amdgcn_global_load_lds(AS1(a0 + k0), AS3(As + ch0 * 512), 16, 0, 0);
    __builtin_amdgcn_global_load_lds(AS1(a1 + k0), AS3(As + ch0 * 512 + 512), 16, 0, 0);
    __builtin_amdgcn_global_load_lds(AS1(b0 + k0), AS3(Bs + ch0 * 512), 16, 0, 0);
    __builtin_amdgcn_global_load_lds(AS1(b1 + k0), AS3(Bs + ch0 * 512 + 512), 16, 0, 0);
    __builtin_amdgcn_s_waitcnt(0);
    __syncthreads();

    bf16x8 af[4], bfr[4];
    #pragma unroll
    for (int i = 0; i < 4; i++)
      af[i] = *(const bf16x8*)(As + (wm + i * 16 + c) * 32 + (g ^ fswz) * 8);
    #pragma unroll
    for (int j = 0; j < 4; j++)
      bfr[j] = *(const bf16x8*)(Bs + (wn + j * 16 + c) * 32 + (g ^ fswz) * 8);
    #pragma unroll
    for (int i = 0; i < 4; i++)
      #pragma unroll
      for (int j = 0; j < 4; j++)
        acc[i][j] = MFMA_BF16(af[i], bfr[j], acc[i][j], 0, 0, 0);
  }

  #pragma unroll
  for (int i = 0; i < 4; i++)
    #pragma unroll
    for (int j = 0; j < 4; j++)
      #pragma unroll
      for (int r = 0; r < 4; r++) {
        size_t idx = (size_t)(m0 + wm + i * 16 + g * 4 + r) * N + n0 + wn + j * 16 + c;
        if constexpr (sizeof(OutT) == 2) C[idx] = f2bf(acc[i][j][r]);
        else                             C[idx] = acc[i][j][r];
      }
}

// ---------------- RMSNorm + RoPE for Q and K heads (bf16 QKV input) ----------------
// SC = log2(e)/sqrt(64) folded into Q here (attention uses exp2 with fixed max 0).
// 4 tasks per wave to amortize wave launch overhead.
__global__ __launch_bounds__(256) void norm_rope(const unsigned short* __restrict__ QKV,
                                                 const float* __restrict__ cosb,
                                                 const float* __restrict__ sinb,
                                                 const float* __restrict__ q_scale,
                                                 const float* __restrict__ k_scale,
                                                 unsigned short* __restrict__ Qn,
                                                 unsigned short* __restrict__ Kn) {
  const int tid = threadIdx.x, w = tid >> 6, d = tid & 63;
  const float qs = q_scale[d], ks = k_scale[d];
  #pragma unroll
  for (int k = 0; k < 4; k++) {
    int task = blockIdx.x * 16 + w * 4 + k;
    const int hid = task % 40;
    const int row = task / 40;            // b*2048 + s
    const int b = row >> 11, s = row & 2047;
    float val, sc;
    if (hid < 32) {
      val = bf2f(QKV[(size_t)row * 3072 + hid * 64 + d]);
      sc = qs;
    } else {
      val = bf2f(QKV[(size_t)row * 3072 + 2048 + (hid - 32) * 64 + d]);
      sc = ks;
    }
    float v2 = val * val;
    #pragma unroll
    for (int off = 32; off; off >>= 1) v2 += __shfl_xor(v2, off);
    float t = val * (1.0f / sqrtf(v2 * (1.0f / 64.0f) + 1e-6f)) * sc;
    float partner = __shfl_xor(t, 32);
    float rot = (d < 32) ? -partner : partner;
    float o = t * cosb[s * 64 + d] + rot * sinb[s * 64 + d];
    if (hid < 32) o *= 0.18033688011112042f;   // fold softmax scale into Q
    unsigned short ob = f2bf(o);
    if (hid < 32) Qn[((size_t)(b * 32 + hid) * 2048 + s) * 64 + d] = ob;
    else          Kn[((size_t)(b * 8 + (hid - 32)) * 2048 + s) * 64 + d] = ob;
  }
}

// ---------------- V transpose: bf16 QKV V-cols -> Vt bf16 [b][kv][D][S] ----------------
__global__ __launch_bounds__(256) void v_transpose(const unsigned short* __restrict__ QKV,
                                                   unsigned short* __restrict__ Vt) {
  __shared__ unsigned int t[64][65];
  int bid = blockIdx.x;
  const int st = bid & 31, kv = (bid >> 5) & 7, b = bid >> 8;
  const int tid = threadIdx.x, lane = tid & 63, quad = tid >> 6;
  #pragma unroll
  for (int p = 0; p < 16; p++) {
    int sl = p * 4 + quad;
    t[sl][lane] = QKV[(size_t)(b * 2048 + st * 64 + sl) * 3072 + 2560 + kv * 64 + lane];
  }
  __syncthreads();
  size_t base = (size_t)(b * 8 + kv) * 64 * 2048;
  #pragma unroll
  for (int p = 0; p < 16; p++) {
    int dd = p * 4 + quad;
    Vt[base + (size_t)dd * 2048 + st * 64 + lane] = (unsigned short)t[lane][dd];
  }
}

// ---------------- causal flash attention v6 ----------------
// v5 structure (4 independent waves/block, each owning a full head x 32-q-row
// causal walk; no combine, no __syncthreads) with the K double-buffer replaced
// by an IN-PLACE reload: ak is dead once the QK MFMAs issue, so the next tile's
// K loads overwrite it (WAR, compiler nops) — same prefetch distance, -32 VGPRs
// -> target <=128 VGPR = 4 waves/SIMD (R6 was 148 -> 3 waves/SIMD, 11% occ).
__global__ __launch_bounds__(256) void attn_kernel(const unsigned short* __restrict__ Qn,
                                                   const unsigned short* __restrict__ Kn,
                                                   const unsigned short* __restrict__ Vt,
                                                   unsigned short* __restrict__ Outv) {
  __shared__ alignas(16) char smem[4 * 4352];

  const int tid = threadIdx.x, w = tid >> 6, lane = tid & 63;
  const int g = lane >> 4, c = lane & 15;
  const int bid = blockIdx.x;                      // [0, 1024)
  const int qt = 63 - (bid >> 4);                  // longest blocks first
  const int rem = bid & 15;
  const int hg = rem & 7, b = rem >> 3;
  const int h = hg * 4 + w;
  const int kvh = hg;
  const int Q0 = qt * 32;
  const unsigned short* Qp = Qn + ((size_t)(b * NHEADS + h) * S_LEN + Q0) * HDIM;
  const unsigned short* Kp = Kn + (size_t)(b * NKV + kvh) * S_LEN * HDIM;
  const unsigned short* Vp = Vt + (size_t)(b * NKV + kvh) * HDIM * S_LEN;  // [d][s]
  const int ntiles = (qt >> 1) + 1;
  char* PwB = smem + w * 4352;   // this wave's P buffer (32 rows x 128 B, swizzled)

  // Q as B-operand: B[k=d][n=q], n = c, k = g*8+j (+t*32)
  bf16x8 bq[2][2];
  #pragma unroll
  for (int iq = 0; iq < 2; iq++)
    #pragma unroll
    for (int t = 0; t < 2; t++)
      bq[iq][t] = *(const bf16x8*)(Qp + (size_t)(iq * 16 + c) * HDIM + t * 32 + g * 8);

  f32x4 OT[4][2] = {};          // O^T tiles: [dt][iq], row=d, col=q
  f32x4 lv[2] = {};             // per-lane l partials

  bf16x8 ak[4][2];              // current K tile (A-operand: A[m=kv][k=d])
  #pragma unroll
  for (int jt = 0; jt < 4; jt++)
    #pragma unroll
    for (int t = 0; t < 2; t++)
      ak[jt][t] = *(const bf16x8*)(Kp + (size_t)(jt * 16 + c) * HDIM + t * 32 + g * 8);

  for (int ti = 0; ti < ntiles; ti++) {
    const int kv0 = ti * 64;

    // V tile (A-operand: A[m=d][k=kv]) — issued early, consumed after softmax
    bf16x8 av[4][2];
    #pragma unroll
    for (int dt = 0; dt < 4; dt++)
      #pragma unroll
      for (int t = 0; t < 2; t++)
        av[dt][t] = *(const bf16x8*)(Vp + (size_t)(dt * 16 + c) * S_LEN + kv0 + t * 32 + g * 8);

    // S^T = K · Q^T : rows kv, cols q
    f32x4 Sx[4][2] = {};
    #pragma unroll
    for (int t = 0; t < 2; t++)
      #pragma unroll
      for (int jt = 0; jt < 4; jt++)
        #pragma unroll
        for (int iq = 0; iq < 2; iq++)
          Sx[jt][iq] = MFMA_BF16(ak[jt][t], bq[iq][t], Sx[jt][iq], 0, 0, 0);

    // in-place prefetch of next K tile (ak dead after QK MFMAs issue; WAR only)
    if (ti + 1 < ntiles) {
      const int kvn = kv0 + 64;
      #pragma unroll
      for (int jt = 0; jt < 4; jt++)
        #pragma unroll
        for (int t = 0; t < 2; t++)
          ak[jt][t] = *(const bf16x8*)(Kp + (size_t)(kvn + jt * 16 + c) * HDIM + t * 32 + g * 8);
    }

    if (ti == ntiles - 1) {     // only the final tile crosses the diagonal
      #pragma unroll
      for (int jt = 0; jt < 4; jt++)
        #pragma unroll
        for (int iq = 0; iq < 2; iq++)
          #pragma unroll
          for (int r = 0; r < 4; r++) {
            int kv = kv0 + jt * 16 + g * 4 + r;
            int q  = Q0 + iq * 16 + c;
            if (kv > q) Sx[jt][iq][r] = -1e30f;
          }
    }

    // fixed-max softmax: p = exp2(s); accumulate l per-lane; pack P -> LDS (swizzled)
    #pragma unroll
    for (int jt = 0; jt < 4; jt++)
      #pragma unroll
      for (int iq = 0; iq < 2; iq++) {
        f32x4 p;
        #pragma unroll
        for (int r = 0; r < 4; r++) p[r] = EXP2F(Sx[jt][iq][r]);
        lv[iq] += p;
        uint32_t u0 = __float_as_uint(p[0]) + 0x8000u;
        uint32_t u1 = __float_as_uint(p[1]) + 0x8000u;
        uint32_t u2 = __float_as_uint(p[2]) + 0x8000u;
        uint32_t u3 = __float_as_uint(p[3]) + 0x8000u;
        uint32_t lo = __builtin_amdgcn_perm(u1, u0, 0x07060302u);
        uint32_t hi = __builtin_amdgcn_perm(u3, u2, 0x07060302u);
        int row = iq * 16 + c;                 // local q
        int bytecol = jt * 32 + g * 8;         // kv-contiguous bytes
        uint32_t off = row * 128 + (((bytecol >> 4) ^ (row & 7)) << 4) + (bytecol & 15);
        *(uint2*)(PwB + off) = make_uint2(lo, hi);
      }
    __builtin_amdgcn_s_waitcnt(0xC07F);        // lgkmcnt(0) only — keep VMEM in flight

    // P as B-operand: B[k=kv][n=q]; read back swizzled b128 (wave-private)
    bf16x8 bp[2][2];
    #pragma unroll
    for (int iq = 0; iq < 2; iq++)
      #pragma unroll
      for (int t = 0; t < 2; t++) {
        int row = iq * 16 + c;
        int bytecol = t * 64 + g * 16;
        uint32_t off = row * 128 + (((bytecol >> 4) ^ (row & 7)) << 4);
        bp[iq][t] = *(const bf16x8*)(PwB + off);
      }
    #pragma unroll
    for (int t = 0; t < 2; t++)
      #pragma unroll
      for (int dt = 0; dt < 4; dt++)
        #pragma unroll
        for (int iq = 0; iq < 2; iq++)
          OT[dt][iq] = MFMA_BF16(av[dt][t], bp[iq][t], OT[dt][iq], 0, 0, 0);
  }

  // l: sum lane partials (kv mod 16 split across g) -> butterfly over g
  float inv[2];
  #pragma unroll
  for (int iq = 0; iq < 2; iq++) {
    float s = lv[iq][0] + lv[iq][1] + lv[iq][2] + lv[iq][3];
    s += __shfl_xor(s, 16);
    s += __shfl_xor(s, 32);
    inv[iq] = 1.0f / s;
  }

  // write O: lane holds d = dt*16+g*4+{0..3}, q = Q0+iq*16+c -> 8B stores
  #pragma unroll
  for (int iq = 0; iq < 2; iq++) {
    const int q = Q0 + iq * 16 + c;
    unsigned short* orow = Outv + (size_t)(b * S_LEN + q) * (NHEADS * HDIM) + h * HDIM;
    #pragma unroll
    for (int dt = 0; dt < 4; dt++) {
      uint32_t u0 = __float_as_uint(OT[dt][iq][0] * inv[iq]) + 0x8000u;
      uint32_t u1 = __float_as_uint(OT[dt][iq][1] * inv[iq]) + 0x8000u;
      uint32_t u2 = __float_as_uint(OT[dt][iq][2] * inv[iq]) + 0x8000u;
      uint32_t u3 = __float_as_uint(OT[dt][iq][3] * inv[iq]) + 0x8000u;
      uint32_t lo = __builtin_amdgcn_perm(u1, u0, 0x07060302u);
      uint32_t hi = __builtin_amdgcn_perm(u3, u2, 0x07060302u);
      *(uint2*)(orow + dt * 16 + g * 4) = make_uint2(lo, hi);
    }
  }
}

extern "C" void kernel_launch(void* const* d_in, const int* in_sizes, int n_in,
                              void* d_out, int out_size, void* d_ws, size_t ws_size,
                              hipStream_t stream) {
  const float* x       = (const float*)d_in[0];
  // d_in[1] = mask (causal, implemented analytically)
  const float* cosb    = (const float*)d_in[2];
  const float* sinb    = (const float*)d_in[3];
  const float* Wq      = (const float*)d_in[4];
  const float* Wk      = (const float*)d_in[5];
  const float* Wv      = (const float*)d_in[6];
  const float* Wo      = (const float*)d_in[7];
  const float* q_scale = (const float*)d_in[8];
  const float* k_scale = (const float*)d_in[9];

  char* ws = (char*)d_ws;
  unsigned short* xb   = (unsigned short*)(ws);                       // 16 MiB: x bf16 [4096][2048]
  unsigned short* wcat = (unsigned short*)(ws + (16ull << 20));       // 12 MiB: Wt [3072][2048]
  unsigned short* wo_t = (unsigned short*)(ws + (28ull << 20));       //  8 MiB: Wo_t [2048][2048]
  unsigned short* qkv  = (unsigned short*)(ws + (36ull << 20));       // 24 MiB: QKV bf16 [4096][3072]
  unsigned short* qn   = (unsigned short*)(ws + (84ull << 20));       // 16 MiB: Q bf16 [b][h][s][d]
  unsigned short* kn   = (unsigned short*)(ws + (100ull << 20));      //  4 MiB: K bf16 [b][kv][s][d]
  unsigned short* vt   = (unsigned short*)(ws + (104ull << 20));      //  4 MiB: V^T bf16 [b][kv][d][s]
  unsigned short* vec  = (unsigned short*)(ws + (36ull << 20));       // alias qkv (dead after v_transpose)

  cast_x_kernel<<<8192, 256, 0, stream>>>(x, xb, 2097152);
  dim3 tb(32, 8);
  transpose_cast_wqkv<<<dim3(96, 64), tb, 0, stream>>>(Wq, Wk, Wv, wcat);
  transpose_cast<<<dim3(64, 64), tb, 0, stream>>>(Wo, wo_t, 2048, 2048);

  gemm_nt<unsigned short><<<dim3(24, 32), 256, 0, stream>>>(xb, wcat, qkv, 4096, 3072, 2048);
  norm_rope<<<10240, 256, 0, stream>>>(qkv, cosb, sinb, q_scale, k_scale, qn, kn);
  v_transpose<<<512, 256, 0, stream>>>(qkv, vt);
  attn_kernel<<<1024, 256, 0, stream>>>(qn, kn, vt, vec);
  gemm_nt<float><<<dim3(16, 32), 256, 0, stream>>>(vec, wo_t, (float*)d_out, 4096, 2048, 2048);
}